// Round 7
// baseline (848.610 us; speedup 1.0000x reference)
//
#include <hip/hip_runtime.h>
#include <math.h>

#define F_IN 256
#define CH   16
#define NL   7

#define BS    64          // nodes per bucket (dL fits 6 bits)
#define CHE   8192        // edges per scatter chunk
#define MAXNB 2048        // LDS cap for bucket arrays (NB=1563 actual)

// ---------------------------------------------------------------- chunk histogram: H[c][b] = #edges of chunk c with dst in bucket b
__global__ __launch_bounds__(1024) void k_hist(const int* __restrict__ dst, int E, int NB,
                                               int* __restrict__ H) {
    __shared__ int h[MAXNB];
    int c = blockIdx.x, tid = threadIdx.x;
    for (int i = tid; i < NB; i += 1024) h[i] = 0;
    __syncthreads();
    int beg = c * CHE, end = min(beg + CHE, E);
    for (int e = beg + tid; e < end; e += 1024) atomicAdd(&h[dst[e] >> 6], 1);
    __syncthreads();
    int* Hrow = H + (size_t)c * NB;
    for (int i = tid; i < NB; i += 1024) Hrow[i] = h[i];
}

// ---------------------------------------------------------------- column sums: total[b] = sum_c H[c][b]
__global__ __launch_bounds__(256) void k_colsum(const int* __restrict__ H, int NB, int C,
                                                int* __restrict__ total) {
    int b = blockIdx.x * 256 + threadIdx.x;
    if (b >= NB) return;
    int s = 0;
#pragma unroll 8
    for (int c = 0; c < C; ++c) s += H[(size_t)c * NB + b];
    total[b] = s;
}

// ---------------------------------------------------------------- exclusive scan of bucket totals (1 WG, 2/thread, NB<=2048)
__global__ __launch_bounds__(1024) void k_scanbase(const int* __restrict__ total, int NB, int E,
                                                   int* __restrict__ base) {
    __shared__ int sm[1024];
    int t = threadIdx.x;
    int i0 = 2 * t, i1 = 2 * t + 1;
    int v0 = (i0 < NB) ? total[i0] : 0;
    int v1 = (i1 < NB) ? total[i1] : 0;
    sm[t] = v0 + v1;
    __syncthreads();
    for (int off = 1; off < 1024; off <<= 1) {
        int u = (t >= off) ? sm[t - off] : 0;
        __syncthreads();
        sm[t] += u;
        __syncthreads();
    }
    int ex = sm[t] - (v0 + v1);
    if (i0 < NB) base[i0] = ex;
    if (i1 < NB) base[i1] = ex + v0;
    if (t == 0) base[NB] = E;
}

// ---------------------------------------------------------------- column scan: H[c][b] <- base[b] + sum_{c'<c} H[c'][b]
__global__ __launch_bounds__(256) void k_colscan(int* __restrict__ H, const int* __restrict__ base,
                                                 int NB, int C) {
    int b = blockIdx.x * 256 + threadIdx.x;
    if (b >= NB) return;
    int run = base[b];
#pragma unroll 8
    for (int c = 0; c < C; ++c) {
        size_t idx = (size_t)c * NB + b;
        int t = H[idx];
        H[idx] = run;
        run += t;
    }
}

// ---------------------------------------------------------------- scatter: LDS-local counting sort per chunk, linear writeout
__global__ __launch_bounds__(1024) void k_scatter2(const int* __restrict__ src, const int* __restrict__ dst,
                                                   int E, int NB, const int* __restrict__ H,
                                                   int* __restrict__ packed) {
    __shared__ int lcur[MAXNB];            // exclusive starts, then running cursors
    __shared__ int ldel[MAXNB];            // global base - local start
    __shared__ int ssc[1024];
    __shared__ int lval[CHE];
    __shared__ unsigned short lbkt[CHE];   // bucket id per local slot
    int c = blockIdx.x, tid = threadIdx.x;
    int beg = c * CHE, end = min(beg + CHE, E), n = end - beg;

    for (int i = tid; i < NB; i += 1024) lcur[i] = 0;
    __syncthreads();
    for (int e = beg + tid; e < end; e += 1024) atomicAdd(&lcur[dst[e] >> 6], 1);
    __syncthreads();

    // exclusive scan of lcur[0..NB), 2 elements per thread
    int i0 = 2 * tid;
    int a0 = (i0 < NB) ? lcur[i0] : 0;
    int a1 = (i0 + 1 < NB) ? lcur[i0 + 1] : 0;
    int tsum = a0 + a1;
    ssc[tid] = tsum;
    __syncthreads();
    for (int off = 1; off < 1024; off <<= 1) {
        int u = (tid >= off) ? ssc[tid - off] : 0;
        __syncthreads();
        ssc[tid] += u;
        __syncthreads();
    }
    int ex = ssc[tid] - tsum;
    if (i0 < NB) lcur[i0] = ex;
    if (i0 + 1 < NB) lcur[i0 + 1] = ex + a0;
    __syncthreads();

    const int* Hrow = H + (size_t)c * NB;
    for (int i = tid; i < NB; i += 1024) ldel[i] = Hrow[i] - lcur[i];
    __syncthreads();

    // place edges into LDS in bucket-sorted local order
    for (int e = beg + tid; e < end; e += 1024) {
        int d = dst[e], s = src[e];
        int bb = d >> 6;
        int p = atomicAdd(&lcur[bb], 1);
        lval[p] = s | ((d & (BS - 1)) << 17);
        lbkt[p] = (unsigned short)bb;
    }
    __syncthreads();

    // linear writeout
    for (int p = tid; p < n; p += 1024)
        packed[ldel[lbkt[p]] + p] = lval[p];
}

// ---------------------------------------------------------------- dinv from bucketed edges
__global__ __launch_bounds__(256) void k_dinv(const int* __restrict__ packed, const int* __restrict__ base,
                                              int N, float* __restrict__ dinv) {
    __shared__ int cnt[BS];
    int b = blockIdx.x, tid = threadIdx.x;
    if (tid < BS) cnt[tid] = 0;
    __syncthreads();
    int beg = base[b], end = base[b + 1];
    for (int e = beg + tid; e < end; e += 256) atomicAdd(&cnt[(packed[e] >> 17) & (BS - 1)], 1);
    __syncthreads();
    int node = b * BS + tid;
    if (tid < BS && node < N) dinv[node] = rsqrtf((float)(cnt[tid] + 1));
}

// ---------------------------------------------------------------- gemm1: g = (x @ W0) * dinv
__global__ __launch_bounds__(256) void k_gemm1(const float* __restrict__ x,
                                               const float* __restrict__ W0,
                                               const float* __restrict__ dinv,
                                               float* __restrict__ g, int N) {
    int lane = threadIdx.x & 63;
    int q = lane >> 4;
    int c = lane & 15;
    float w[64];
#pragma unroll
    for (int t = 0; t < 64; ++t) w[t] = W0[(q * 64 + t) * CH + c];

    int wave  = (blockIdx.x * blockDim.x + threadIdx.x) >> 6;
    int nwave = (gridDim.x * blockDim.x) >> 6;
    for (int row = wave; row < N; row += nwave) {
        const float4* xp = (const float4*)(x + row * F_IN + q * 64);
        float acc = 0.f;
#pragma unroll
        for (int t = 0; t < 16; ++t) {
            float4 v = xp[t];
            acc += v.x * w[4*t] + v.y * w[4*t+1] + v.z * w[4*t+2] + v.w * w[4*t+3];
        }
        acc += __shfl_xor(acc, 16);
        acc += __shfl_xor(acc, 32);
        if (q == 0) g[row * CH + c] = acc * dinv[row];
    }
}

// ---------------------------------------------------------------- layer1 push: accA[dst] += g[src]  (R0-proven flat atomic kernel)
__global__ void k_edge1(const int* __restrict__ src, const int* __restrict__ dst,
                        const float* __restrict__ g, float* __restrict__ accA, int E) {
    long long tid = (long long)blockIdx.x * blockDim.x + threadIdx.x;
    int e = (int)(tid >> 4), c = (int)(tid & 15);
    if (e >= E) return;
    unsafeAtomicAdd(&accA[(size_t)dst[e] * CH + c], g[(size_t)src[e] * CH + c]);
}

// ---------------------------------------------------------------- layer2 transform: g2 = (relu(dinv*(accA+g)) @ W1) * dinv
__global__ __launch_bounds__(256) void k_layer2t(const float* __restrict__ g,
                                                 const float* __restrict__ accA,
                                                 const float* __restrict__ W1,
                                                 const float* __restrict__ dinv,
                                                 float* __restrict__ g2, int N) {
    int tid = blockIdx.x * 256 + threadIdx.x;
    int node = tid >> 4, c = tid & 15;
    if (node >= N) return;
    float dv = dinv[node];
    float h = fmaxf((accA[(size_t)node * CH + c] + g[(size_t)node * CH + c]) * dv, 0.f);
    float w1[NL];
#pragma unroll
    for (int j = 0; j < NL; ++j) w1[j] = W1[c * NL + j];
    float y = 0.f;
#pragma unroll
    for (int j = 0; j < NL; ++j) {
        float p = h * w1[j];
        p += __shfl_xor(p, 8, 16);
        p += __shfl_xor(p, 4, 16);
        p += __shfl_xor(p, 2, 16);
        p += __shfl_xor(p, 1, 16);
        if (c == j) y = p;
    }
    if (c < 8) g2[(size_t)node * 8 + c] = (c < NL) ? y * dv : 0.f;
}

// ---------------------------------------------------------------- agg2: pull from L2-resident g2 (3.2 MB) + exp epilogue
__global__ __launch_bounds__(1024) void k_agg2(const float* __restrict__ g2,
                                               const int* __restrict__ packed,
                                               const int* __restrict__ base,
                                               const float* __restrict__ dinv,
                                               float* __restrict__ out, int N) {
    __shared__ float acc[BS * 8];    // 2 KB
    int b = blockIdx.x, tid = threadIdx.x;
    int j = tid & 7, er = tid >> 3;
    for (int i = tid; i < BS * 8; i += 1024) acc[i] = 0.f;
    __syncthreads();

    int beg = base[b], end = base[b + 1];
    for (int eb = beg; eb < end; eb += 1024) {
        int v[8]; float xv[8]; bool pr[8];
#pragma unroll
        for (int k = 0; k < 8; ++k) {
            int e = eb + k * 128 + er;
            pr[k] = e < end;
            v[k] = pr[k] ? __builtin_nontemporal_load(packed + e) : 0;
        }
#pragma unroll
        for (int k = 0; k < 8; ++k)
            xv[k] = pr[k] ? g2[(v[k] & 0x1FFFF) * 8 + j] : 0.f;
#pragma unroll
        for (int k = 0; k < 8; ++k)
            if (pr[k]) atomicAdd(&acc[((v[k] >> 17) & (BS - 1)) * 8 + j], xv[k]);
    }
    __syncthreads();

    if (tid < BS * 8) {
        int nL = tid >> 3;
        int node = b * BS + nL;
        if (node < N && j < NL) {
            float dv = dinv[node];
            out[(size_t)node * NL + j] = __expf((acc[nL * 8 + j] + g2[node * 8 + j]) * dv) + 1.0f;
        }
    }
}

extern "C" void kernel_launch(void* const* d_in, const int* in_sizes, int n_in,
                              void* d_out, int out_size, void* d_ws, size_t ws_size,
                              hipStream_t stream) {
    const float* x  = (const float*)d_in[0];
    const float* W0 = (const float*)d_in[1];
    const float* W1 = (const float*)d_in[2];
    const int*   ei = (const int*)d_in[3];

    const int N = in_sizes[0] / F_IN;       // 100000
    const int E = in_sizes[3] / 2;          // 3200000
    const int* src = ei;
    const int* dst = ei + E;

    const int NB = (N + BS - 1) / BS;       // 1563
    const int C  = (E + CHE - 1) / CHE;     // 391

    // workspace (~31.7 MB):
    // H[C*NB] | base[NB+1] | total[NB] | pad | packed[E] | dinv[N] | g[N*16] | g2[N*8] | accA[N*16]
    int* H       = (int*)d_ws;
    int* base    = H + (size_t)C * NB;
    int* total   = base + (NB + 1);
    int* packed  = total + NB + 64;
    float* dinv  = (float*)(packed + E);
    float* g     = dinv + N;
    float* g2    = g + (size_t)N * CH;
    float* accA  = g2 + (size_t)N * 8;

    float* out = (float*)d_out;

    // zero the layer-1 accumulator (6.4 MB)
    hipMemsetAsync(accA, 0, (size_t)N * CH * sizeof(float), stream);

    // 1) per-chunk bucket histograms
    k_hist<<<C, 1024, 0, stream>>>(dst, E, NB, H);

    // 2) bucket bases
    k_colsum<<<(NB + 255) / 256, 256, 0, stream>>>(H, NB, C, total);
    k_scanbase<<<1, 1024, 0, stream>>>(total, NB, E, base);
    k_colscan<<<(NB + 255) / 256, 256, 0, stream>>>(H, base, NB, C);

    // 3) chunked counting-sort scatter (dst-bucketed edges for agg2 + dinv)
    k_scatter2<<<C, 1024, 0, stream>>>(src, dst, E, NB, H, packed);

    // 4) dinv from bucketed edges (no global atomics)
    k_dinv<<<NB, 256, 0, stream>>>(packed, base, N, dinv);

    // 5) g = (x@W0) * dinv   [N][16]
    k_gemm1<<<2048, 256, 0, stream>>>(x, W0, dinv, g, N);

    // 6) layer1 via flat atomic PUSH (R0-proven 168 us; beats pull's 340)
    {
        long long tot = (long long)E * CH;
        k_edge1<<<(int)((tot + 255) / 256), 256, 0, stream>>>(src, dst, g, accA, E);
    }

    // 7) layer2 transform: relu + W1 + dinv -> g2[N][8]  (streamed, ~5 us)
    k_layer2t<<<(N * 16 + 255) / 256, 256, 0, stream>>>(g, accA, W1, dinv, g2, N);

    // 8) layer2 aggregate via pull + fused exp epilogue
    k_agg2<<<NB, 1024, 0, stream>>>(g2, packed, base, dinv, out, N);
}

// Round 8
// 668.332 us; speedup vs baseline: 1.2697x; 1.2697x over previous
//
#include <hip/hip_runtime.h>
#include <math.h>

#define F_IN 256
#define CH   16
#define NL   7

#define BS    64          // nodes per bucket (dL fits 6 bits)
#define CHE   8192        // edges per scatter chunk
#define MAXNB 2048        // LDS cap for bucket arrays (NB=1563 actual)
#define NSEG  8           // segments for the column scan

// ---------------------------------------------------------------- chunk histogram: H[c][b] = #edges of chunk c with dst in bucket b
__global__ __launch_bounds__(1024) void k_hist(const int* __restrict__ dst, int E, int NB,
                                               int* __restrict__ H) {
    __shared__ int h[MAXNB];
    int c = blockIdx.x, tid = threadIdx.x;
    for (int i = tid; i < NB; i += 1024) h[i] = 0;
    __syncthreads();
    int beg = c * CHE, end = min(beg + CHE, E);
    for (int e = beg + tid; e < end; e += 1024) atomicAdd(&h[dst[e] >> 6], 1);
    __syncthreads();
    int* Hrow = H + (size_t)c * NB;
    for (int i = tid; i < NB; i += 1024) Hrow[i] = h[i];
}

// ---------------------------------------------------------------- segmented column sums: S[s][b] = sum_{c in seg s} H[c][b]
__global__ __launch_bounds__(256) void k_colsum8(const int* __restrict__ H, int NB, int C,
                                                 int seglen, int* __restrict__ S) {
    int b = blockIdx.x * 256 + threadIdx.x;
    int s = blockIdx.y;
    if (b >= NB) return;
    int c0 = s * seglen, c1 = min(c0 + seglen, C);
    int acc = 0;
    for (int c = c0; c < c1; ++c) acc += H[(size_t)c * NB + b];
    S[(size_t)s * NB + b] = acc;
}

// ---------------------------------------------------------------- total[b] = sum_s S[s][b]
__global__ __launch_bounds__(256) void k_tot(const int* __restrict__ S, int NB,
                                             int* __restrict__ total) {
    int b = blockIdx.x * 256 + threadIdx.x;
    if (b >= NB) return;
    int acc = 0;
#pragma unroll
    for (int s = 0; s < NSEG; ++s) acc += S[(size_t)s * NB + b];
    total[b] = acc;
}

// ---------------------------------------------------------------- exclusive scan of bucket totals (1 WG, 2/thread, NB<=2048)
__global__ __launch_bounds__(1024) void k_scanbase(const int* __restrict__ total, int NB, int E,
                                                   int* __restrict__ base) {
    __shared__ int sm[1024];
    int t = threadIdx.x;
    int i0 = 2 * t, i1 = 2 * t + 1;
    int v0 = (i0 < NB) ? total[i0] : 0;
    int v1 = (i1 < NB) ? total[i1] : 0;
    sm[t] = v0 + v1;
    __syncthreads();
    for (int off = 1; off < 1024; off <<= 1) {
        int u = (t >= off) ? sm[t - off] : 0;
        __syncthreads();
        sm[t] += u;
        __syncthreads();
    }
    int ex = sm[t] - (v0 + v1);
    if (i0 < NB) base[i0] = ex;
    if (i1 < NB) base[i1] = ex + v0;
    if (t == 0) base[NB] = E;
}

// ---------------------------------------------------------------- per-segment start: SB[s][b] = base[b] + sum_{s'<s} S[s'][b]
__global__ __launch_bounds__(256) void k_segoff(const int* __restrict__ S, const int* __restrict__ base,
                                                int NB, int* __restrict__ SB) {
    int b = blockIdx.x * 256 + threadIdx.x;
    if (b >= NB) return;
    int run = base[b];
#pragma unroll
    for (int s = 0; s < NSEG; ++s) {
        SB[(size_t)s * NB + b] = run;
        run += S[(size_t)s * NB + b];
    }
}

// ---------------------------------------------------------------- segmented column scan: H[c][b] <- absolute start offset
__global__ __launch_bounds__(256) void k_colscan8(int* __restrict__ H, const int* __restrict__ SB,
                                                  int NB, int C, int seglen) {
    int b = blockIdx.x * 256 + threadIdx.x;
    int s = blockIdx.y;
    if (b >= NB) return;
    int c0 = s * seglen, c1 = min(c0 + seglen, C);
    int run = SB[(size_t)s * NB + b];
    for (int c = c0; c < c1; ++c) {
        size_t idx = (size_t)c * NB + b;
        int t = H[idx];
        H[idx] = run;
        run += t;
    }
}

// ---------------------------------------------------------------- scatter: LDS-local counting sort per chunk, linear writeout
__global__ __launch_bounds__(1024) void k_scatter2(const int* __restrict__ src, const int* __restrict__ dst,
                                                   int E, int NB, const int* __restrict__ H,
                                                   int* __restrict__ packed) {
    __shared__ int lcur[MAXNB];            // exclusive starts, then running cursors
    __shared__ int ldel[MAXNB];            // global base - local start
    __shared__ int ssc[1024];
    __shared__ int lval[CHE];
    __shared__ unsigned short lbkt[CHE];   // bucket id per local slot
    int c = blockIdx.x, tid = threadIdx.x;
    int beg = c * CHE, end = min(beg + CHE, E), n = end - beg;

    for (int i = tid; i < NB; i += 1024) lcur[i] = 0;
    __syncthreads();
    for (int e = beg + tid; e < end; e += 1024) atomicAdd(&lcur[dst[e] >> 6], 1);
    __syncthreads();

    // exclusive scan of lcur[0..NB), 2 elements per thread
    int i0 = 2 * tid;
    int a0 = (i0 < NB) ? lcur[i0] : 0;
    int a1 = (i0 + 1 < NB) ? lcur[i0 + 1] : 0;
    int tsum = a0 + a1;
    ssc[tid] = tsum;
    __syncthreads();
    for (int off = 1; off < 1024; off <<= 1) {
        int u = (tid >= off) ? ssc[tid - off] : 0;
        __syncthreads();
        ssc[tid] += u;
        __syncthreads();
    }
    int ex = ssc[tid] - tsum;
    if (i0 < NB) lcur[i0] = ex;
    if (i0 + 1 < NB) lcur[i0 + 1] = ex + a0;
    __syncthreads();

    const int* Hrow = H + (size_t)c * NB;
    for (int i = tid; i < NB; i += 1024) ldel[i] = Hrow[i] - lcur[i];
    __syncthreads();

    // place edges into LDS in bucket-sorted local order
    for (int e = beg + tid; e < end; e += 1024) {
        int d = dst[e], s = src[e];
        int bb = d >> 6;
        int p = atomicAdd(&lcur[bb], 1);
        lval[p] = s | ((d & (BS - 1)) << 17);
        lbkt[p] = (unsigned short)bb;
    }
    __syncthreads();

    // linear writeout
    for (int p = tid; p < n; p += 1024)
        packed[ldel[lbkt[p]] + p] = lval[p];
}

// ---------------------------------------------------------------- dinv from bucketed edges
__global__ __launch_bounds__(256) void k_dinv(const int* __restrict__ packed, const int* __restrict__ base,
                                              int N, float* __restrict__ dinv) {
    __shared__ int cnt[BS];
    int b = blockIdx.x, tid = threadIdx.x;
    if (tid < BS) cnt[tid] = 0;
    __syncthreads();
    int beg = base[b], end = base[b + 1];
    for (int e = beg + tid; e < end; e += 256) atomicAdd(&cnt[(packed[e] >> 17) & (BS - 1)], 1);
    __syncthreads();
    int node = b * BS + tid;
    if (tid < BS && node < N) dinv[node] = rsqrtf((float)(cnt[tid] + 1));
}

// ---------------------------------------------------------------- gemm1: g = (x @ W0) * dinv
__global__ __launch_bounds__(256) void k_gemm1(const float* __restrict__ x,
                                               const float* __restrict__ W0,
                                               const float* __restrict__ dinv,
                                               float* __restrict__ g, int N) {
    int lane = threadIdx.x & 63;
    int q = lane >> 4;
    int c = lane & 15;
    float w[64];
#pragma unroll
    for (int t = 0; t < 64; ++t) w[t] = W0[(q * 64 + t) * CH + c];

    int wave  = (blockIdx.x * blockDim.x + threadIdx.x) >> 6;
    int nwave = (gridDim.x * blockDim.x) >> 6;
    for (int row = wave; row < N; row += nwave) {
        const float4* xp = (const float4*)(x + row * F_IN + q * 64);
        float acc = 0.f;
#pragma unroll
        for (int t = 0; t < 16; ++t) {
            float4 v = xp[t];
            acc += v.x * w[4*t] + v.y * w[4*t+1] + v.z * w[4*t+2] + v.w * w[4*t+3];
        }
        acc += __shfl_xor(acc, 16);
        acc += __shfl_xor(acc, 32);
        if (q == 0) g[row * CH + c] = acc * dinv[row];
    }
}

// ---------------------------------------------------------------- layer1 push: accA[dst] += g[src]  (R0-proven; 64B-aligned rows!)
__global__ void k_edge1(const int* __restrict__ src, const int* __restrict__ dst,
                        const float* __restrict__ g, float* __restrict__ accA, int E) {
    long long tid = (long long)blockIdx.x * blockDim.x + threadIdx.x;
    int e = (int)(tid >> 4), c = (int)(tid & 15);
    if (e >= E) return;
    unsafeAtomicAdd(&accA[(size_t)dst[e] * CH + c], g[(size_t)src[e] * CH + c]);
}

// ---------------------------------------------------------------- layer2 transform: g2 = (relu(dinv*(accA+g)) @ W1) * dinv
__global__ __launch_bounds__(256) void k_layer2t(const float* __restrict__ g,
                                                 const float* __restrict__ accA,
                                                 const float* __restrict__ W1,
                                                 const float* __restrict__ dinv,
                                                 float* __restrict__ g2, int N) {
    int tid = blockIdx.x * 256 + threadIdx.x;
    int node = tid >> 4, c = tid & 15;
    if (node >= N) return;
    float dv = dinv[node];
    float h = fmaxf((accA[(size_t)node * CH + c] + g[(size_t)node * CH + c]) * dv, 0.f);
    float w1[NL];
#pragma unroll
    for (int j = 0; j < NL; ++j) w1[j] = W1[c * NL + j];
    float y = 0.f;
#pragma unroll
    for (int j = 0; j < NL; ++j) {
        float p = h * w1[j];
        p += __shfl_xor(p, 8, 16);
        p += __shfl_xor(p, 4, 16);
        p += __shfl_xor(p, 2, 16);
        p += __shfl_xor(p, 1, 16);
        if (c == j) y = p;
    }
    if (c < 8) g2[(size_t)node * 8 + c] = (c < NL) ? y * dv : 0.f;
}

// ---------------------------------------------------------------- agg2: pull from L2-resident g2 (3.2 MB, aligned) + exp epilogue
__global__ __launch_bounds__(1024) void k_agg2(const float* __restrict__ g2,
                                               const int* __restrict__ packed,
                                               const int* __restrict__ base,
                                               const float* __restrict__ dinv,
                                               float* __restrict__ out, int N) {
    __shared__ float acc[BS * 8];    // 2 KB
    int b = blockIdx.x, tid = threadIdx.x;
    int j = tid & 7, er = tid >> 3;
    for (int i = tid; i < BS * 8; i += 1024) acc[i] = 0.f;
    __syncthreads();

    int beg = base[b], end = base[b + 1];
    for (int eb = beg; eb < end; eb += 1024) {
        int v[8]; float xv[8]; bool pr[8];
#pragma unroll
        for (int k = 0; k < 8; ++k) {
            int e = eb + k * 128 + er;
            pr[k] = e < end;
            v[k] = pr[k] ? __builtin_nontemporal_load(packed + e) : 0;
        }
#pragma unroll
        for (int k = 0; k < 8; ++k)
            xv[k] = pr[k] ? g2[(v[k] & 0x1FFFF) * 8 + j] : 0.f;
#pragma unroll
        for (int k = 0; k < 8; ++k)
            if (pr[k]) atomicAdd(&acc[((v[k] >> 17) & (BS - 1)) * 8 + j], xv[k]);
    }
    __syncthreads();

    if (tid < BS * 8) {
        int nL = tid >> 3;
        int node = b * BS + nL;
        if (node < N && j < NL) {
            float dv = dinv[node];
            out[(size_t)node * NL + j] = __expf((acc[nL * 8 + j] + g2[node * 8 + j]) * dv) + 1.0f;
        }
    }
}

static inline size_t align64(size_t n) { return (n + 63) & ~(size_t)63; }  // 64 elems = 256 B

extern "C" void kernel_launch(void* const* d_in, const int* in_sizes, int n_in,
                              void* d_out, int out_size, void* d_ws, size_t ws_size,
                              hipStream_t stream) {
    const float* x  = (const float*)d_in[0];
    const float* W0 = (const float*)d_in[1];
    const float* W1 = (const float*)d_in[2];
    const int*   ei = (const int*)d_in[3];

    const int N = in_sizes[0] / F_IN;       // 100000
    const int E = in_sizes[3] / 2;          // 3200000
    const int* src = ei;
    const int* dst = ei + E;

    const int NB = (N + BS - 1) / BS;       // 1563
    const int C  = (E + CHE - 1) / CHE;     // 391
    const int SEGLEN = (C + NSEG - 1) / NSEG;  // 49
    const int NBG = (NB + 255) / 256;       // 7

    // workspace (all buffers 256B-aligned; ~31.8 MB):
    // H[C*NB] | S[8*NB] | SB[8*NB] | base[NB+1] | total[NB] | packed[E] | dinv[N] | g[N*16] | g2[N*8] | accA[N*16]
    size_t off = 0;
    int* H       = (int*)d_ws + off;           off += align64((size_t)C * NB);
    int* S       = (int*)d_ws + off;           off += align64((size_t)NSEG * NB);
    int* SB      = (int*)d_ws + off;           off += align64((size_t)NSEG * NB);
    int* base    = (int*)d_ws + off;           off += align64((size_t)NB + 1);
    int* total   = (int*)d_ws + off;           off += align64((size_t)NB);
    int* packed  = (int*)d_ws + off;           off += align64((size_t)E);
    float* dinv  = (float*)d_ws + off;         off += align64((size_t)N);
    float* g     = (float*)d_ws + off;         off += align64((size_t)N * CH);
    float* g2    = (float*)d_ws + off;         off += align64((size_t)N * 8);
    float* accA  = (float*)d_ws + off;         off += align64((size_t)N * CH);

    float* out = (float*)d_out;

    // zero the layer-1 accumulator (6.4 MB)
    hipMemsetAsync(accA, 0, (size_t)N * CH * sizeof(float), stream);

    // 1) per-chunk bucket histograms
    k_hist<<<C, 1024, 0, stream>>>(dst, E, NB, H);

    // 2) bucket bases: segmented column scan (coalesced over b, 8x parallel over c)
    k_colsum8<<<dim3(NBG, NSEG), 256, 0, stream>>>(H, NB, C, SEGLEN, S);
    k_tot<<<NBG, 256, 0, stream>>>(S, NB, total);
    k_scanbase<<<1, 1024, 0, stream>>>(total, NB, E, base);
    k_segoff<<<NBG, 256, 0, stream>>>(S, base, NB, SB);
    k_colscan8<<<dim3(NBG, NSEG), 256, 0, stream>>>(H, SB, NB, C, SEGLEN);

    // 3) chunked counting-sort scatter (dst-bucketed edges for agg2 + dinv)
    k_scatter2<<<C, 1024, 0, stream>>>(src, dst, E, NB, H, packed);

    // 4) dinv from bucketed edges (no global atomics)
    k_dinv<<<NB, 256, 0, stream>>>(packed, base, N, dinv);

    // 5) g = (x@W0) * dinv   [N][16], 64B-aligned rows
    k_gemm1<<<2048, 256, 0, stream>>>(x, W0, dinv, g, N);

    // 6) layer1 via flat atomic PUSH (aligned accA/g rows: 1 line-RMW + 1 line-fetch per edge)
    {
        long long tot = (long long)E * CH;
        k_edge1<<<(int)((tot + 255) / 256), 256, 0, stream>>>(src, dst, g, accA, E);
    }

    // 7) layer2 transform: relu + W1 + dinv -> g2[N][8]
    k_layer2t<<<(N * 16 + 255) / 256, 256, 0, stream>>>(g, accA, W1, dinv, g2, N);

    // 8) layer2 aggregate via pull + fused exp epilogue
    k_agg2<<<NB, 1024, 0, stream>>>(g2, packed, base, dinv, out, N);
}